// Round 7
// baseline (926.826 us; speedup 1.0000x reference)
//
#include <hip/hip_runtime.h>
#include <hip/hip_bf16.h>
#include <hip/hip_fp16.h>

#define DD 64
#define EPSV 1e-5f

static __device__ __forceinline__ float fatomic_add(float* p, float v) {
#if defined(__HIP_DEVICE_COMPILE__)
    return unsafeAtomicAdd(p, v);
#else
    return 0.f;
#endif
}

static __device__ __forceinline__ float gelu_exact(float x) {
    return 0.5f * x * (1.0f + erff(x * 0.70710678118654752f));
}

// ---------------- CSR build ----------------
__global__ void k_hist(const int* __restrict__ dst, int* __restrict__ counts, int e) {
    int i = blockIdx.x * 256 + threadIdx.x;
    if (i < e) atomicAdd(&counts[dst[i]], 1);
}

// single-workgroup tiled scan, fused: counts[n] -> off[n+1] (exclusive),
// dinv[i] = rsqrt(counts[i]+1), cursor written IN-PLACE over counts.
__global__ __launch_bounds__(1024) void k_scan_fused(int* __restrict__ counts,
                                                     int* __restrict__ off,
                                                     float* __restrict__ dinv,
                                                     int n, int etotal) {
    __shared__ int wsum[16];
    __shared__ int carry_s, tile_tot;
    int t = threadIdx.x;
    int lane = t & 63, wv = t >> 6;
    if (t == 0) carry_s = 0;
    __syncthreads();
    for (int base = 0; base < n; base += 1024) {
        int i = base + t;
        int v = (i < n) ? counts[i] : 0;
        int x = v;
#pragma unroll
        for (int o = 1; o < 64; o <<= 1) {
            int u = __shfl_up(x, o, 64);
            if (lane >= o) x += u;
        }
        if (lane == 63) wsum[wv] = x;
        __syncthreads();
        if (t == 0) {
            int r = 0;
#pragma unroll
            for (int w = 0; w < 16; ++w) { int y = wsum[w]; wsum[w] = r; r += y; }
            tile_tot = r;
        }
        __syncthreads();
        int excl = carry_s + wsum[wv] + x - v;
        if (i < n) {
            off[i] = excl;
            dinv[i] = rsqrtf((float)v + 1.0f);  // +1 self-loop
            counts[i] = excl;                    // becomes cursor for k_fill
        }
        __syncthreads();
        if (t == 0) carry_s += tile_tot;
        __syncthreads();
    }
    if (t == 0) off[n] = etotal;
}

// csr entry: {src_index, dinv[src] as bits}
__global__ void k_fill(const int* __restrict__ src, const int* __restrict__ dst,
                       const float* __restrict__ dinv,
                       int* __restrict__ cursor, int2* __restrict__ csr, int e) {
    int i = blockIdx.x * 256 + threadIdx.x;
    if (i < e) {
        int d = dst[i];
        int s = src[i];
        int pos = atomicAdd(&cursor[d], 1);
        csr[pos] = make_int2(s, __float_as_int(dinv[s]));
    }
}

// ---------------- graph boundaries from sorted batch: bnd[g]..bnd[g+1] ----------------
__global__ void k_bounds(const int* __restrict__ batch, int* __restrict__ bnd, int n, int g) {
    int i = blockIdx.x * 256 + threadIdx.x;
    if (i >= n) return;
    int b = batch[i];
    if (i == 0)
        for (int q = 0; q <= b; ++q) bnd[q] = 0;
    else {
        int pb = batch[i - 1];
        for (int q = pb + 1; q <= b; ++q) bnd[q] = i;
    }
    if (i == n - 1)
        for (int q = b + 1; q <= g; ++q) bnd[q] = n;
}

// ---------------- x -> fp16 mirror, plus zero gstats (3 layers x 128 floats) ----------------
__global__ void k_xtohalf(const float* __restrict__ x, __half* __restrict__ m,
                          int total, float* __restrict__ gstats) {
    int i = blockIdx.x * 256 + threadIdx.x;
    if (blockIdx.x == 0 && threadIdx.x < 384) gstats[threadIdx.x] = 0.f;
    if (i < total) m[i] = __float2half_rn(x[i]);
}

// ---------------- fused: fp16 8-edge gather (4-deep prefetch) -> row GEMM -> BN stats ----------------
// agg[d,:] = (dinv[d]*(dinv[d]*h[d,:] + sum_e dinv[s]*h[s,:])) @ W + convB
__global__ __launch_bounds__(256) void k_gather_gemm(const int* __restrict__ off,
                                                     const int2* __restrict__ csr,
                                                     const float* __restrict__ dinv,
                                                     const uint4* __restrict__ m16,
                                                     const float* __restrict__ W,
                                                     const float* __restrict__ convB,
                                                     float* __restrict__ agg,
                                                     float* __restrict__ gsum,
                                                     float* __restrict__ gsumsq, int n) {
    __shared__ float Wl[64 * 64];
    int t = threadIdx.x;
    for (int i = t; i < 64 * 64; i += 256) Wl[i] = W[i];
    int lane = t & 63, wv = t >> 6;
    int oct = lane >> 3;   // which edge of an 8-group this lane gathers
    int sub = lane & 7;    // which 16B chunk (8 cols) of the row
    float bias = convB[lane];
    float s = 0.f, sq = 0.f;
    __syncthreads();
    for (int node = blockIdx.x * 4 + wv; node < n; node += gridDim.x * 4) {
        int a = off[node], b = off[node + 1];
        float dd = dinv[node];
        uint4 vself = m16[(size_t)node * 8 + sub];  // issue early: self-row load in flight
        float acc[8];
#pragma unroll
        for (int p = 0; p < 8; ++p) acc[p] = 0.f;
        for (int base = a; base < b; base += 64) {
            int rem = b - base;
            int cnt = rem < 64 ? rem : 64;
            int2 ent = make_int2(0, 0);  // zero-fill: tail entries -> row 0, w=0
            if (lane < cnt) ent = csr[base + lane];
            int nblk = (cnt + 7) >> 3;   // 1..8, wave-uniform
            // ---- prefetch phase 1: up to 4 loads in flight ----
            uint4 v[4];
#pragma unroll
            for (int p = 0; p < 4; ++p)
                if (p < nblk) {
                    int sn = __shfl(ent.x, p * 8 + oct, 64);
                    v[p] = m16[(size_t)sn * 8 + sub];
                }
#pragma unroll
            for (int p = 0; p < 4; ++p)
                if (p < nblk) {
                    float w = __int_as_float(__shfl(ent.y, p * 8 + oct, 64));
                    const __half2* h2 = reinterpret_cast<const __half2*>(&v[p]);
#pragma unroll
                    for (int q = 0; q < 4; ++q) {
                        float2 f = __half22float2(h2[q]);
                        acc[2 * q]     += w * f.x;
                        acc[2 * q + 1] += w * f.y;
                    }
                }
            // ---- rare phase 2: degrees 33..64 within this group ----
            if (nblk > 4) {
                uint4 v2[4];
#pragma unroll
                for (int p = 4; p < 8; ++p)
                    if (p < nblk) {
                        int sn = __shfl(ent.x, p * 8 + oct, 64);
                        v2[p - 4] = m16[(size_t)sn * 8 + sub];
                    }
#pragma unroll
                for (int p = 4; p < 8; ++p)
                    if (p < nblk) {
                        float w = __int_as_float(__shfl(ent.y, p * 8 + oct, 64));
                        const __half2* h2 = reinterpret_cast<const __half2*>(&v2[p - 4]);
#pragma unroll
                        for (int q = 0; q < 4; ++q) {
                            float2 f = __half22float2(h2[q]);
                            acc[2 * q]     += w * f.x;
                            acc[2 * q + 1] += w * f.y;
                        }
                    }
            }
        }
        // reduce across octs: lanes with equal sub sum up
#pragma unroll
        for (int p = 0; p < 8; ++p) {
            acc[p] += __shfl_xor(acc[p], 8, 64);
            acc[p] += __shfl_xor(acc[p], 16, 64);
            acc[p] += __shfl_xor(acc[p], 32, 64);
        }
        // self-loop + outer dinv scale (cols 8*sub + p)
        {
            const __half2* h2 = reinterpret_cast<const __half2*>(&vself);
#pragma unroll
            for (int q = 0; q < 4; ++q) {
                float2 f = __half22float2(h2[q]);
                acc[2 * q]     = (acc[2 * q]     + dd * f.x) * dd;
                acc[2 * q + 1] = (acc[2 * q + 1] + dd * f.y) * dd;
            }
        }
        // row GEMM: column c's value is component (c&7) of lane (c>>3)
        float r0 = bias, r1 = 0.f, r2 = 0.f, r3 = 0.f;
#pragma unroll
        for (int c = 0; c < 64; c += 4) {
            r0 += __shfl(acc[(c + 0) & 7], (c + 0) >> 3, 64) * Wl[(c + 0) * 64 + lane];
            r1 += __shfl(acc[(c + 1) & 7], (c + 1) >> 3, 64) * Wl[(c + 1) * 64 + lane];
            r2 += __shfl(acc[(c + 2) & 7], (c + 2) >> 3, 64) * Wl[(c + 2) * 64 + lane];
            r3 += __shfl(acc[(c + 3) & 7], (c + 3) >> 3, 64) * Wl[(c + 3) * 64 + lane];
        }
        float r = (r0 + r1) + (r2 + r3);
        agg[(size_t)node * 64 + lane] = r;
        s += r;
        sq += r * r;
    }
    __shared__ float ls[256], lq[256];
    ls[t] = s;
    lq[t] = sq;
    __syncthreads();
    if (t < 64) {
        float fs = ls[t] + ls[t + 64] + ls[t + 128] + ls[t + 192];
        float fq = lq[t] + lq[t + 64] + lq[t + 128] + lq[t + 192];
        fatomic_add(&gsum[t], fs);
        fatomic_add(&gsumsq[t], fq);
    }
}

// ---------------- BN + residual + LN + GELU (+ fp16 mirror of output) ----------------
__global__ __launch_bounds__(256) void k_bn_ln_gelu(const float* __restrict__ agg,
                                                    const float* __restrict__ xin,
                                                    const float* __restrict__ gsum,
                                                    const float* __restrict__ gsumsq,
                                                    const float* __restrict__ bng,
                                                    const float* __restrict__ bnb,
                                                    const float* __restrict__ lng,
                                                    const float* __restrict__ lnb,
                                                    float* __restrict__ out,
                                                    __half* __restrict__ m16,
                                                    int n, int has_res, int write_m) {
    int t = threadIdx.x;
    int lane = t & 63, wv = t >> 6;
    float invN = 1.0f / (float)n;
    float mu_c = gsum[lane] * invN;
    float var_c = gsumsq[lane] * invN - mu_c * mu_c;
    float bscale = rsqrtf(var_c + EPSV) * bng[lane];
    float bshift = bnb[lane];
    float lg = lng[lane], lb = lnb[lane];
    for (int r = blockIdx.x * 4 + wv; r < n; r += gridDim.x * 4) {
        float x = agg[(size_t)r * 64 + lane];
        float hb = (x - mu_c) * bscale + bshift;
        if (has_res) hb += xin[(size_t)r * 64 + lane];
        float ssum = hb;
#pragma unroll
        for (int off = 32; off; off >>= 1) ssum += __shfl_xor(ssum, off, 64);
        float rmu = ssum * (1.f / 64.f);
        float d = hb - rmu;
        float vs = d * d;
#pragma unroll
        for (int off = 32; off; off >>= 1) vs += __shfl_xor(vs, off, 64);
        float rvar = vs * (1.f / 64.f);
        float ln = d * rsqrtf(rvar + EPSV) * lg + lb;
        float g = gelu_exact(ln);
        out[(size_t)r * 64 + lane] = g;
        if (write_m) m16[(size_t)r * 64 + lane] = __float2half_rn(g);
    }
}

// ---------------- pooling: one block per graph (4 waves split rows) ----------------
__global__ __launch_bounds__(256) void k_pool_z(const float* __restrict__ h,
                                                const int* __restrict__ bnd,
                                                float* __restrict__ z) {
    int g = blockIdx.x;
    int t = threadIdx.x;
    int lane = t & 63, wv = t >> 6;
    int s0 = bnd[g], e0 = bnd[g + 1];
    float s = 0.f, mx = -INFINITY;
    for (int i = s0 + wv; i < e0; i += 4) {
        float v = h[(size_t)i * 64 + lane];
        s += v;
        mx = fmaxf(mx, v);
    }
    __shared__ float ss[256], sm[256];
    ss[t] = s;
    sm[t] = mx;
    __syncthreads();
    if (t < 64) {
        float fs = ss[t] + ss[t + 64] + ss[t + 128] + ss[t + 192];
        float fm = fmaxf(fmaxf(sm[t], sm[t + 64]), fmaxf(sm[t + 128], sm[t + 192]));
        float cntf = (float)(e0 - s0);
        float mean = fs / fmaxf(cntf, 1.0f);
        if (e0 == s0) fm = 0.f;
        z[g * 192 + t] = mean;
        z[g * 192 + 64 + t] = fm;
        z[g * 192 + 128 + t] = fs;
    }
}

// ---------------- MLP head (one block per graph) ----------------
__global__ __launch_bounds__(128) void k_head(const float* __restrict__ z,
                                              const float* __restrict__ W1, const float* __restrict__ b1,
                                              const float* __restrict__ ln1g, const float* __restrict__ ln1b,
                                              const float* __restrict__ W2, const float* __restrict__ b2,
                                              const float* __restrict__ ln2g, const float* __restrict__ ln2b,
                                              const float* __restrict__ W3, const float* __restrict__ b3,
                                              float* __restrict__ out) {
    int g = blockIdx.x;
    int t = threadIdx.x;
    int lane = t & 63, wv = t >> 6;
    __shared__ float zl[192], h1[128], red[2];
    for (int i = t; i < 192; i += 128) zl[i] = z[g * 192 + i];
    __syncthreads();
    float acc = b1[t];
    for (int k = 0; k < 192; ++k) acc += zl[k] * W1[k * 128 + t];
    float s = acc;
#pragma unroll
    for (int off = 32; off; off >>= 1) s += __shfl_xor(s, off, 64);
    if (lane == 0) red[wv] = s;
    __syncthreads();
    float mu = (red[0] + red[1]) * (1.f / 128.f);
    float d = acc - mu;
    float q = d * d;
#pragma unroll
    for (int off = 32; off; off >>= 1) q += __shfl_xor(q, off, 64);
    __syncthreads();
    if (lane == 0) red[wv] = q;
    __syncthreads();
    float var = (red[0] + red[1]) * (1.f / 128.f);
    float ln = d * rsqrtf(var + EPSV) * ln1g[t] + ln1b[t];
    h1[t] = gelu_exact(ln);
    __syncthreads();
    if (t < 64) {
        float acc2 = b2[t];
        for (int k = 0; k < 128; ++k) acc2 += h1[k] * W2[k * 64 + t];
        float s2 = acc2;
#pragma unroll
        for (int off = 32; off; off >>= 1) s2 += __shfl_xor(s2, off, 64);
        float mu2 = s2 * (1.f / 64.f);
        float d2 = acc2 - mu2;
        float q2 = d2 * d2;
#pragma unroll
        for (int off = 32; off; off >>= 1) q2 += __shfl_xor(q2, off, 64);
        float var2 = q2 * (1.f / 64.f);
        float l2 = d2 * rsqrtf(var2 + EPSV) * ln2g[t] + ln2b[t];
        float g2 = gelu_exact(l2);
        float p = g2 * W3[t];
#pragma unroll
        for (int off = 32; off; off >>= 1) p += __shfl_xor(p, off, 64);
        if (t == 0) out[g] = p + b3[0];
    }
}

extern "C" void kernel_launch(void* const* d_in, const int* in_sizes, int n_in,
                              void* d_out, int out_size, void* d_ws, size_t ws_size,
                              hipStream_t stream) {
    const float* x      = (const float*)d_in[0];
    const int*   eidx   = (const int*)d_in[1];
    const int*   batch  = (const int*)d_in[2];
    const float* convW  = (const float*)d_in[3];
    const float* convB  = (const float*)d_in[4];
    const float* bn_g   = (const float*)d_in[5];
    const float* bn_b   = (const float*)d_in[6];
    const float* ln_g   = (const float*)d_in[7];
    const float* ln_b   = (const float*)d_in[8];
    const float* W1     = (const float*)d_in[9];
    const float* b1     = (const float*)d_in[10];
    const float* ln1g   = (const float*)d_in[11];
    const float* ln1b   = (const float*)d_in[12];
    const float* W2     = (const float*)d_in[13];
    const float* b2     = (const float*)d_in[14];
    const float* ln2g   = (const float*)d_in[15];
    const float* ln2b   = (const float*)d_in[16];
    const float* W3     = (const float*)d_in[17];
    const float* b3     = (const float*)d_in[18];
    float* out = (float*)d_out;

    const int N = in_sizes[0] / DD;
    const int E = in_sizes[1] / 2;
    const int G = out_size;
    const int* esrc = eidx;
    const int* edst = eidx + E;

    char* ws = (char*)d_ws;
    size_t off_b = 0;
    auto alloc = [&](size_t bytes) {
        size_t p = off_b;
        off_b = (off_b + bytes + 255) & ~(size_t)255;
        return (void*)(ws + p);
    };
    // layout total ~77.6 MB (< 77.86 MB proven safe in R1):
    int*    offs   = (int*)alloc((size_t)(N + 1) * 4);
    float*  dinv   = (float*)alloc((size_t)N * 4);
    int2*   csr    = (int2*)alloc((size_t)E * 8);
    __half* m16    = (__half*)alloc((size_t)N * DD * 2);
    float*  bufA   = (float*)alloc((size_t)N * DD * 4);
    float*  bufB   = (float*)alloc((size_t)N * DD * 4);
    float*  gstats = (float*)alloc(3 * 2 * DD * 4);  // 3 layers x (gsum|gsumsq)
    int*    bnd    = (int*)alloc((size_t)(G + 1) * 4);
    // aliases into dead regions:
    int*   counts = (int*)bufA;   // live only during CSR build (before L0 gather)
    float* z      = (float*)bufB; // live only after L2 bn consumed bufB
    (void)ws_size; (void)n_in;

    // ---- CSR build (once per launch) ----
    hipMemsetAsync(counts, 0, (size_t)N * 4, stream);
    k_hist<<<(E + 255) / 256, 256, 0, stream>>>(edst, counts, E);
    k_scan_fused<<<1, 1024, 0, stream>>>(counts, offs, dinv, N, E);  // counts -> cursor in-place
    k_fill<<<(E + 255) / 256, 256, 0, stream>>>(esrc, edst, dinv, counts, csr, E);
    k_bounds<<<(N + 255) / 256, 256, 0, stream>>>(batch, bnd, N, G);
    k_xtohalf<<<(N * DD + 255) / 256, 256, 0, stream>>>(x, m16, N * DD, gstats);

    // rotation: L0: gather(m16 of x)->A, bn: A(+none)->A, m16=h1
    //           L1: gather(m16)->B,      bn: B + res A -> B, m16=h2
    //           L2: gather(m16)->A,      bn: A + res B -> A
    const float* res[3] = {nullptr, bufA, bufB};
    float* ag[3] = {bufA, bufB, bufA};

    for (int l = 0; l < 3; ++l) {
        float* gsum = gstats + l * 128;
        float* gsumsq = gsum + 64;
        k_gather_gemm<<<2048, 256, 0, stream>>>(offs, csr, dinv, (const uint4*)m16,
                                                convW + (size_t)l * DD * DD, convB + l * DD,
                                                ag[l], gsum, gsumsq, N);
        k_bn_ln_gelu<<<2048, 256, 0, stream>>>(ag[l], l ? res[l] : ag[l], gsum, gsumsq,
                                               bn_g + l * DD, bn_b + l * DD,
                                               ln_g + l * DD, ln_b + l * DD,
                                               ag[l], m16, N, l > 0 ? 1 : 0, l < 2 ? 1 : 0);
    }

    k_pool_z<<<G, 256, 0, stream>>>(bufA, bnd, z);
    k_head<<<G, 128, 0, stream>>>(z, W1, b1, ln1g, ln1b, W2, b2, ln2g, ln2b, W3, b3, out);
}

// Round 8
// 724.497 us; speedup vs baseline: 1.2793x; 1.2793x over previous
//
#include <hip/hip_runtime.h>
#include <hip/hip_bf16.h>
#include <hip/hip_fp16.h>

#define DD 64
#define EPSV 1e-5f

static __device__ __forceinline__ float fatomic_add(float* p, float v) {
#if defined(__HIP_DEVICE_COMPILE__)
    return unsafeAtomicAdd(p, v);
#else
    return 0.f;
#endif
}

static __device__ __forceinline__ float gelu_exact(float x) {
    return 0.5f * x * (1.0f + erff(x * 0.70710678118654752f));
}

// ---------------- CSR build ----------------
__global__ void k_hist(const int* __restrict__ dst, int* __restrict__ counts, int e) {
    int i = blockIdx.x * 256 + threadIdx.x;
    if (i < e) atomicAdd(&counts[dst[i]], 1);
}

// parallel scan pass 1: per-block sums of counts tiles (1024/block)
__global__ __launch_bounds__(1024) void k_bsum(const int* __restrict__ counts,
                                               int* __restrict__ bsum, int n) {
    __shared__ int wsum[16];
    int t = threadIdx.x;
    int i = blockIdx.x * 1024 + t;
    int v = (i < n) ? counts[i] : 0;
    int lane = t & 63, wv = t >> 6;
    int x = v;
#pragma unroll
    for (int o = 1; o < 64; o <<= 1) x += __shfl_xor(x, o, 64);
    if (lane == 0) wsum[wv] = x;
    __syncthreads();
    if (t == 0) {
        int r = 0;
#pragma unroll
        for (int w = 0; w < 16; ++w) r += wsum[w];
        bsum[blockIdx.x] = r;
    }
}

// parallel scan pass 2: exclusive scan of block sums (single small block)
__global__ __launch_bounds__(128) void k_bscan(int* __restrict__ bsum, int nb) {
    __shared__ int ws[2];
    int t = threadIdx.x;
    int lane = t & 63, wv = t >> 6;
    int v = (t < nb) ? bsum[t] : 0;
    int x = v;
#pragma unroll
    for (int o = 1; o < 64; o <<= 1) {
        int u = __shfl_up(x, o, 64);
        if (lane >= o) x += u;
    }
    if (lane == 63) ws[wv] = x;
    __syncthreads();
    int add = (wv == 1) ? ws[0] : 0;
    if (t < nb) bsum[t] = add + x - v;  // exclusive
}

// parallel scan pass 3: per-tile exclusive scan + bsum offset; writes off/dinv, cursor in-place
__global__ __launch_bounds__(1024) void k_downsweep(int* __restrict__ counts,
                                                    const int* __restrict__ bsum,
                                                    int* __restrict__ off,
                                                    float* __restrict__ dinv,
                                                    int n, int etotal) {
    __shared__ int wsum[16];
    int t = threadIdx.x;
    int i = blockIdx.x * 1024 + t;
    int v = (i < n) ? counts[i] : 0;
    int lane = t & 63, wv = t >> 6;
    int x = v;
#pragma unroll
    for (int o = 1; o < 64; o <<= 1) {
        int u = __shfl_up(x, o, 64);
        if (lane >= o) x += u;
    }
    if (lane == 63) wsum[wv] = x;
    __syncthreads();
    if (t == 0) {
        int r = 0;
#pragma unroll
        for (int w = 0; w < 16; ++w) { int y = wsum[w]; wsum[w] = r; r += y; }
    }
    __syncthreads();
    if (i < n) {
        int excl = bsum[blockIdx.x] + wsum[wv] + x - v;
        off[i] = excl;
        dinv[i] = rsqrtf((float)v + 1.0f);  // +1 self-loop
        counts[i] = excl;                    // becomes cursor for k_fill
        if (i == n - 1) off[n] = etotal;
    }
}

// csr entry: {src_index, dinv[src] as bits}
__global__ void k_fill(const int* __restrict__ src, const int* __restrict__ dst,
                       const float* __restrict__ dinv,
                       int* __restrict__ cursor, int2* __restrict__ csr, int e) {
    int i = blockIdx.x * 256 + threadIdx.x;
    if (i < e) {
        int d = dst[i];
        int s = src[i];
        int pos = atomicAdd(&cursor[d], 1);
        csr[pos] = make_int2(s, __float_as_int(dinv[s]));
    }
}

// ---------------- graph boundaries from sorted batch: bnd[g]..bnd[g+1] ----------------
__global__ void k_bounds(const int* __restrict__ batch, int* __restrict__ bnd, int n, int g) {
    int i = blockIdx.x * 256 + threadIdx.x;
    if (i >= n) return;
    int b = batch[i];
    if (i == 0)
        for (int q = 0; q <= b; ++q) bnd[q] = 0;
    else {
        int pb = batch[i - 1];
        for (int q = pb + 1; q <= b; ++q) bnd[q] = i;
    }
    if (i == n - 1)
        for (int q = b + 1; q <= g; ++q) bnd[q] = n;
}

// ---------------- x -> fp16 mirror, plus zero gstats (3 layers x 128 floats) ----------------
__global__ void k_xtohalf(const float* __restrict__ x, __half* __restrict__ m,
                          int total, float* __restrict__ gstats) {
    int i = blockIdx.x * 256 + threadIdx.x;
    if (blockIdx.x == 0 && threadIdx.x < 384) gstats[threadIdx.x] = 0.f;
    if (i < total) m[i] = __float2half_rn(x[i]);
}

// ---------------- fused: fp16 8-edge gather -> row GEMM -> BN col stats ----------------
// EXACT R6 structure: VGPR 64, 8 edges in flight, no deep prefetch (R7 showed the
// occupancy cliff at VGPR 88 costs more than the extra in-flight loads gain).
__global__ __launch_bounds__(256) void k_gather_gemm(const int* __restrict__ off,
                                                     const int2* __restrict__ csr,
                                                     const float* __restrict__ dinv,
                                                     const uint4* __restrict__ m16,
                                                     const float* __restrict__ W,
                                                     const float* __restrict__ convB,
                                                     float* __restrict__ agg,
                                                     float* __restrict__ gsum,
                                                     float* __restrict__ gsumsq, int n) {
    __shared__ float Wl[64 * 64];
    int t = threadIdx.x;
    for (int i = t; i < 64 * 64; i += 256) Wl[i] = W[i];
    int lane = t & 63, wv = t >> 6;
    int oct = lane >> 3;   // which edge of an 8-group this lane gathers
    int sub = lane & 7;    // which 16B chunk (8 cols) of the row
    float bias = convB[lane];
    float s = 0.f, sq = 0.f;
    __syncthreads();
    for (int node = blockIdx.x * 4 + wv; node < n; node += gridDim.x * 4) {
        int a = off[node], b = off[node + 1];
        float dd = dinv[node];
        float acc[8];
#pragma unroll
        for (int p = 0; p < 8; ++p) acc[p] = 0.f;
        for (int base = a; base < b; base += 64) {
            int rem = b - base;
            int cnt = rem < 64 ? rem : 64;
            int2 ent = make_int2(0, 0);  // zero-fill: tail lanes get w=0 on row 0
            if (lane < cnt) ent = csr[base + lane];
            for (int jj = 0; jj < cnt; jj += 8) {
                int j = jj + oct;  // <= 63 always
                int sn = __shfl(ent.x, j, 64);
                float w = __int_as_float(__shfl(ent.y, j, 64));
                uint4 v = m16[(size_t)sn * 8 + sub];
                const __half2* h2 = reinterpret_cast<const __half2*>(&v);
#pragma unroll
                for (int p = 0; p < 4; ++p) {
                    float2 f = __half22float2(h2[p]);
                    acc[2 * p]     += w * f.x;
                    acc[2 * p + 1] += w * f.y;
                }
            }
        }
        // reduce across octs: lanes with equal sub sum up
#pragma unroll
        for (int p = 0; p < 8; ++p) {
            acc[p] += __shfl_xor(acc[p], 8, 64);
            acc[p] += __shfl_xor(acc[p], 16, 64);
            acc[p] += __shfl_xor(acc[p], 32, 64);
        }
        // self-loop + outer dinv scale (cols 8*sub + p)
        {
            uint4 v = m16[(size_t)node * 8 + sub];
            const __half2* h2 = reinterpret_cast<const __half2*>(&v);
#pragma unroll
            for (int p = 0; p < 4; ++p) {
                float2 f = __half22float2(h2[p]);
                acc[2 * p]     = (acc[2 * p]     + dd * f.x) * dd;
                acc[2 * p + 1] = (acc[2 * p + 1] + dd * f.y) * dd;
            }
        }
        // row GEMM: column c's value is component (c&7) of lane (c>>3)
        float r0 = bias, r1 = 0.f, r2 = 0.f, r3 = 0.f;
#pragma unroll
        for (int c = 0; c < 64; c += 4) {
            r0 += __shfl(acc[(c + 0) & 7], (c + 0) >> 3, 64) * Wl[(c + 0) * 64 + lane];
            r1 += __shfl(acc[(c + 1) & 7], (c + 1) >> 3, 64) * Wl[(c + 1) * 64 + lane];
            r2 += __shfl(acc[(c + 2) & 7], (c + 2) >> 3, 64) * Wl[(c + 2) * 64 + lane];
            r3 += __shfl(acc[(c + 3) & 7], (c + 3) >> 3, 64) * Wl[(c + 3) * 64 + lane];
        }
        float r = (r0 + r1) + (r2 + r3);
        agg[(size_t)node * 64 + lane] = r;
        s += r;
        sq += r * r;
    }
    __shared__ float ls[256], lq[256];
    ls[t] = s;
    lq[t] = sq;
    __syncthreads();
    if (t < 64) {
        float fs = ls[t] + ls[t + 64] + ls[t + 128] + ls[t + 192];
        float fq = lq[t] + lq[t + 64] + lq[t + 128] + lq[t + 192];
        fatomic_add(&gsum[t], fs);
        fatomic_add(&gsumsq[t], fq);
    }
}

// ---------------- BN + residual + LN + GELU (+ fp16 mirror of output) ----------------
__global__ __launch_bounds__(256) void k_bn_ln_gelu(const float* __restrict__ agg,
                                                    const float* __restrict__ xin,
                                                    const float* __restrict__ gsum,
                                                    const float* __restrict__ gsumsq,
                                                    const float* __restrict__ bng,
                                                    const float* __restrict__ bnb,
                                                    const float* __restrict__ lng,
                                                    const float* __restrict__ lnb,
                                                    float* __restrict__ out,
                                                    __half* __restrict__ m16,
                                                    int n, int has_res, int write_m) {
    int t = threadIdx.x;
    int lane = t & 63, wv = t >> 6;
    float invN = 1.0f / (float)n;
    float mu_c = gsum[lane] * invN;
    float var_c = gsumsq[lane] * invN - mu_c * mu_c;
    float bscale = rsqrtf(var_c + EPSV) * bng[lane];
    float bshift = bnb[lane];
    float lg = lng[lane], lb = lnb[lane];
    for (int r = blockIdx.x * 4 + wv; r < n; r += gridDim.x * 4) {
        float x = agg[(size_t)r * 64 + lane];
        float hb = (x - mu_c) * bscale + bshift;
        if (has_res) hb += xin[(size_t)r * 64 + lane];
        float ssum = hb;
#pragma unroll
        for (int off = 32; off; off >>= 1) ssum += __shfl_xor(ssum, off, 64);
        float rmu = ssum * (1.f / 64.f);
        float d = hb - rmu;
        float vs = d * d;
#pragma unroll
        for (int off = 32; off; off >>= 1) vs += __shfl_xor(vs, off, 64);
        float rvar = vs * (1.f / 64.f);
        float ln = d * rsqrtf(rvar + EPSV) * lg + lb;
        float g = gelu_exact(ln);
        out[(size_t)r * 64 + lane] = g;
        if (write_m) m16[(size_t)r * 64 + lane] = __float2half_rn(g);
    }
}

// ---------------- pooling: one block per graph (4 waves split rows) ----------------
__global__ __launch_bounds__(256) void k_pool_z(const float* __restrict__ h,
                                                const int* __restrict__ bnd,
                                                float* __restrict__ z) {
    int g = blockIdx.x;
    int t = threadIdx.x;
    int lane = t & 63, wv = t >> 6;
    int s0 = bnd[g], e0 = bnd[g + 1];
    float s = 0.f, mx = -INFINITY;
    for (int i = s0 + wv; i < e0; i += 4) {
        float v = h[(size_t)i * 64 + lane];
        s += v;
        mx = fmaxf(mx, v);
    }
    __shared__ float ss[256], sm[256];
    ss[t] = s;
    sm[t] = mx;
    __syncthreads();
    if (t < 64) {
        float fs = ss[t] + ss[t + 64] + ss[t + 128] + ss[t + 192];
        float fm = fmaxf(fmaxf(sm[t], sm[t + 64]), fmaxf(sm[t + 128], sm[t + 192]));
        float cntf = (float)(e0 - s0);
        float mean = fs / fmaxf(cntf, 1.0f);
        if (e0 == s0) fm = 0.f;
        z[g * 192 + t] = mean;
        z[g * 192 + 64 + t] = fm;
        z[g * 192 + 128 + t] = fs;
    }
}

// ---------------- MLP head (one block per graph) ----------------
__global__ __launch_bounds__(128) void k_head(const float* __restrict__ z,
                                              const float* __restrict__ W1, const float* __restrict__ b1,
                                              const float* __restrict__ ln1g, const float* __restrict__ ln1b,
                                              const float* __restrict__ W2, const float* __restrict__ b2,
                                              const float* __restrict__ ln2g, const float* __restrict__ ln2b,
                                              const float* __restrict__ W3, const float* __restrict__ b3,
                                              float* __restrict__ out) {
    int g = blockIdx.x;
    int t = threadIdx.x;
    int lane = t & 63, wv = t >> 6;
    __shared__ float zl[192], h1[128], red[2];
    for (int i = t; i < 192; i += 128) zl[i] = z[g * 192 + i];
    __syncthreads();
    float acc = b1[t];
    for (int k = 0; k < 192; ++k) acc += zl[k] * W1[k * 128 + t];
    float s = acc;
#pragma unroll
    for (int off = 32; off; off >>= 1) s += __shfl_xor(s, off, 64);
    if (lane == 0) red[wv] = s;
    __syncthreads();
    float mu = (red[0] + red[1]) * (1.f / 128.f);
    float d = acc - mu;
    float q = d * d;
#pragma unroll
    for (int off = 32; off; off >>= 1) q += __shfl_xor(q, off, 64);
    __syncthreads();
    if (lane == 0) red[wv] = q;
    __syncthreads();
    float var = (red[0] + red[1]) * (1.f / 128.f);
    float ln = d * rsqrtf(var + EPSV) * ln1g[t] + ln1b[t];
    h1[t] = gelu_exact(ln);
    __syncthreads();
    if (t < 64) {
        float acc2 = b2[t];
        for (int k = 0; k < 128; ++k) acc2 += h1[k] * W2[k * 64 + t];
        float s2 = acc2;
#pragma unroll
        for (int off = 32; off; off >>= 1) s2 += __shfl_xor(s2, off, 64);
        float mu2 = s2 * (1.f / 64.f);
        float d2 = acc2 - mu2;
        float q2 = d2 * d2;
#pragma unroll
        for (int off = 32; off; off >>= 1) q2 += __shfl_xor(q2, off, 64);
        float var2 = q2 * (1.f / 64.f);
        float l2 = d2 * rsqrtf(var2 + EPSV) * ln2g[t] + ln2b[t];
        float g2 = gelu_exact(l2);
        float p = g2 * W3[t];
#pragma unroll
        for (int off = 32; off; off >>= 1) p += __shfl_xor(p, off, 64);
        if (t == 0) out[g] = p + b3[0];
    }
}

extern "C" void kernel_launch(void* const* d_in, const int* in_sizes, int n_in,
                              void* d_out, int out_size, void* d_ws, size_t ws_size,
                              hipStream_t stream) {
    const float* x      = (const float*)d_in[0];
    const int*   eidx   = (const int*)d_in[1];
    const int*   batch  = (const int*)d_in[2];
    const float* convW  = (const float*)d_in[3];
    const float* convB  = (const float*)d_in[4];
    const float* bn_g   = (const float*)d_in[5];
    const float* bn_b   = (const float*)d_in[6];
    const float* ln_g   = (const float*)d_in[7];
    const float* ln_b   = (const float*)d_in[8];
    const float* W1     = (const float*)d_in[9];
    const float* b1     = (const float*)d_in[10];
    const float* ln1g   = (const float*)d_in[11];
    const float* ln1b   = (const float*)d_in[12];
    const float* W2     = (const float*)d_in[13];
    const float* b2     = (const float*)d_in[14];
    const float* ln2g   = (const float*)d_in[15];
    const float* ln2b   = (const float*)d_in[16];
    const float* W3     = (const float*)d_in[17];
    const float* b3     = (const float*)d_in[18];
    float* out = (float*)d_out;

    const int N = in_sizes[0] / DD;
    const int E = in_sizes[1] / 2;
    const int G = out_size;
    const int* esrc = eidx;
    const int* edst = eidx + E;

    char* ws = (char*)d_ws;
    size_t off_b = 0;
    auto alloc = [&](size_t bytes) {
        size_t p = off_b;
        off_b = (off_b + bytes + 255) & ~(size_t)255;
        return (void*)(ws + p);
    };
    // layout total ~77.6 MB (< 77.86 MB proven safe in R1):
    int*    offs   = (int*)alloc((size_t)(N + 1) * 4);
    float*  dinv   = (float*)alloc((size_t)N * 4);
    int2*   csr    = (int2*)alloc((size_t)E * 8);
    __half* m16    = (__half*)alloc((size_t)N * DD * 2);
    float*  bufA   = (float*)alloc((size_t)N * DD * 4);
    float*  bufB   = (float*)alloc((size_t)N * DD * 4);
    float*  gstats = (float*)alloc(3 * 2 * DD * 4);  // 3 layers x (gsum|gsumsq)
    int*    bnd    = (int*)alloc((size_t)(G + 1) * 4);
    int*    bsum   = (int*)alloc(((size_t)(N + 1023) / 1024) * 4);
    // aliases into dead regions:
    int*   counts = (int*)bufA;   // live only during CSR build (before L0 gather)
    float* z      = (float*)bufB; // live only after L2 bn consumed bufB
    (void)ws_size; (void)n_in;

    const int nb = (N + 1023) / 1024;

    // ---- CSR build (once per launch), fully parallel scan ----
    hipMemsetAsync(counts, 0, (size_t)N * 4, stream);
    k_hist<<<(E + 255) / 256, 256, 0, stream>>>(edst, counts, E);
    k_bsum<<<nb, 1024, 0, stream>>>(counts, bsum, N);
    k_bscan<<<1, 128, 0, stream>>>(bsum, nb);
    k_downsweep<<<nb, 1024, 0, stream>>>(counts, bsum, offs, dinv, N, E);
    k_fill<<<(E + 255) / 256, 256, 0, stream>>>(esrc, edst, dinv, counts, csr, E);
    k_bounds<<<(N + 255) / 256, 256, 0, stream>>>(batch, bnd, N, G);
    k_xtohalf<<<(N * DD + 255) / 256, 256, 0, stream>>>(x, m16, N * DD, gstats);

    // rotation: L0: gather(m16 of x)->A, bn: A(+none)->A, m16=h1
    //           L1: gather(m16)->B,      bn: B + res A -> B, m16=h2
    //           L2: gather(m16)->A,      bn: A + res B -> A
    const float* res[3] = {nullptr, bufA, bufB};
    float* ag[3] = {bufA, bufB, bufA};

    for (int l = 0; l < 3; ++l) {
        float* gsum = gstats + l * 128;
        float* gsumsq = gsum + 64;
        k_gather_gemm<<<2048, 256, 0, stream>>>(offs, csr, dinv, (const uint4*)m16,
                                                convW + (size_t)l * DD * DD, convB + l * DD,
                                                ag[l], gsum, gsumsq, N);
        k_bn_ln_gelu<<<2048, 256, 0, stream>>>(ag[l], l ? res[l] : ag[l], gsum, gsumsq,
                                               bn_g + l * DD, bn_b + l * DD,
                                               ln_g + l * DD, ln_b + l * DD,
                                               ag[l], m16, N, l > 0 ? 1 : 0, l < 2 ? 1 : 0);
    }

    k_pool_z<<<G, 256, 0, stream>>>(bufA, bnd, z);
    k_head<<<G, 128, 0, stream>>>(z, W1, b1, ln1g, ln1b, W2, b2, ln2g, ln2b, W3, b3, out);
}